// Round 4
// baseline (181.253 us; speedup 1.0000x reference)
//
#include <hip/hip_runtime.h>

#define BB 32
#define SS 512
#define DD 768
#define NROW (BB * SS)  // 16384 rows per input

typedef float f32x4 __attribute__((ext_vector_type(4)));
typedef short bf16x8 __attribute__((ext_vector_type(8)));

// order-preserving float -> uint key (monotone under unsigned compare)
__device__ __forceinline__ unsigned fkey(float f) {
  unsigned u = __float_as_uint(f);
  return (u & 0x80000000u) ? ~u : (u | 0x80000000u);
}
__device__ __forceinline__ float fdecode(unsigned k) {
  return __uint_as_float((k & 0x80000000u) ? (k & 0x7fffffffu) : ~k);
}
// f32 -> bf16 round-to-nearest-even
__device__ __forceinline__ unsigned short cvt_bf16(float f) {
  unsigned u = __float_as_uint(f);
  u += 0x7fffu + ((u >> 16) & 1u);
  return (unsigned short)(u >> 16);
}

// ---------------- K0: valid-index compaction + key init ----------------
// one wave per (batch, side): idx[p] = p-th valid row, nv, nt = ceil(nv/256).
__global__ __launch_bounds__(64) void index_kernel(
    const int* __restrict__ mask1, const int* __restrict__ mask2,
    int* __restrict__ idx1, int* __restrict__ idx2,
    int* __restrict__ nv1, int* __restrict__ nv2,
    int* __restrict__ nt1, int* __restrict__ nt2,
    unsigned* __restrict__ rowkey, unsigned* __restrict__ colkey) {
  int side = blockIdx.x & 1, b = blockIdx.x >> 1;
  const int* m = (side ? mask2 : mask1) + b * SS;
  unsigned* key = (side ? colkey : rowkey) + b * SS;
  int* idx = (side ? idx2 : idx1) + b * SS;
  int l = threadIdx.x;
  int nv = 0;
#pragma unroll
  for (int c = 0; c < 8; ++c) {
    int e = c * 64 + l;
    int v = m[e];
    key[e] = 0x007fffffu;  // fkey(-inf)
    unsigned long long bal = __ballot(v != 0);
    int pos = nv + __popcll(bal & ((1ull << l) - 1ull));
    if (v) idx[pos] = e;
    nv += __popcll(bal);
  }
  if (l == 0) {
    (side ? nv2 : nv1)[b] = nv;
    (side ? nt2 : nt1)[b] = (nv + 255) >> 8;
  }
}

// ---------------- K1: normalize valid rows -> bf16, COMPACTED linear ----------------
__global__ __launch_bounds__(256) void norm_cvt_kernel(
    const float* __restrict__ emb1, const float* __restrict__ emb2,
    const int* __restrict__ idx1, const int* __restrict__ idx2,
    const int* __restrict__ nv1, const int* __restrict__ nv2,
    unsigned short* __restrict__ wsA, unsigned short* __restrict__ wsB) {
  int wave = blockIdx.x * 4 + (threadIdx.x >> 6);  // 32768 waves = slots
  int lane = threadIdx.x & 63;
  int side = wave >> 14;
  int pg = wave & 16383;
  int b = pg >> 9, p = pg & 511;
  int nv = (side ? nv2 : nv1)[b];
  if (p >= nv) return;  // wave-uniform skip
  int orig = (side ? idx2 : idx1)[b * SS + p];
  const float* src = (side ? emb2 : emb1) + ((size_t)b * SS + orig) * DD;
  float4 v[3];
  float s = 0.f;
#pragma unroll
  for (int q = 0; q < 3; ++q) {
    v[q] = ((const float4*)src)[q * 64 + lane];
    s += v[q].x * v[q].x + v[q].y * v[q].y + v[q].z * v[q].z + v[q].w * v[q].w;
  }
#pragma unroll
  for (int m = 1; m < 64; m <<= 1) s += __shfl_xor(s, m);
  float inv = 1.0f / fmaxf(sqrtf(s), 1e-8f);
  unsigned short* dst = (side ? wsB : wsA) + ((size_t)b * SS + p) * DD;
#pragma unroll
  for (int q = 0; q < 3; ++q) {
    ushort4 u;
    u.x = cvt_bf16(v[q].x * inv); u.y = cvt_bf16(v[q].y * inv);
    u.z = cvt_bf16(v[q].z * inv); u.w = cvt_bf16(v[q].w * inv);
    *(ushort4*)(dst + q * 256 + lane * 4) = u;  // coalesced
  }
}

// ---------------- K2: 256x256 bf16 MFMA tile + row/col max ----------------
// 8 waves (2 wr x 4 wc), per-wave 128x64 output, BK=64, dbuf gload_lds staging.
__global__ __launch_bounds__(512, 1) void simmax_kernel(
    const unsigned short* __restrict__ wsA, const unsigned short* __restrict__ wsB,
    const int* __restrict__ idx1, const int* __restrict__ idx2,
    const int* __restrict__ nv1, const int* __restrict__ nv2,
    const int* __restrict__ nt1, const int* __restrict__ nt2,
    unsigned* __restrict__ rowkey, unsigned* __restrict__ colkey) {
  int x = blockIdx.x;
  int b = x & 31;          // all tiles of batch b on XCD b&7
  int tile = x >> 5;       // 0..3
  int ti = tile >> 1, tj = tile & 1;
  if (ti >= nt1[b] || tj >= nt2[b]) return;
  int NV1 = nv1[b], NV2 = nv2[b];
  int i0 = ti << 8, j0 = tj << 8;
  __shared__ __align__(16) unsigned short sA[2][256 * 64];
  __shared__ __align__(16) unsigned short sB[2][256 * 64];
  int t = threadIdx.x, l = t & 63, w = t >> 6, wr = w >> 2, wc = w & 3;
  int rsub = l >> 3, csub = l & 7;
  int csw = (csub ^ rsub) << 3;  // XOR-swizzled source chunk (elements)
  const unsigned short* gA = wsA + (size_t)b * SS * DD;
  const unsigned short* gB = wsB + (size_t)b * SS * DD;
  size_t offA[4], offB[4];
#pragma unroll
  for (int j = 0; j < 4; ++j) {
    int rb_ = j * 64 + w * 8;
    int pa = i0 + rb_ + rsub, pb = j0 + rb_ + rsub;
    pa = pa < NV1 - 1 ? pa : NV1 - 1;  // clamp padding to last valid slot
    pb = pb < NV2 - 1 ? pb : NV2 - 1;
    offA[j] = (size_t)pa * DD + csw;
    offB[j] = (size_t)pb * DD + csw;
  }

  f32x4 acc[8][4] = {};

#define STAGE(buf, k0)                                                              \
  {                                                                                 \
    _Pragma("unroll") for (int j = 0; j < 4; ++j) {                                 \
      int rb_ = j * 64 + w * 8;                                                     \
      __builtin_amdgcn_global_load_lds(                                             \
          (const __attribute__((address_space(1))) unsigned int*)(gA + offA[j] + (k0)), \
          (__attribute__((address_space(3))) unsigned int*)&sA[buf][rb_ * 64],      \
          16, 0, 0);                                                                \
      __builtin_amdgcn_global_load_lds(                                             \
          (const __attribute__((address_space(1))) unsigned int*)(gB + offB[j] + (k0)), \
          (__attribute__((address_space(3))) unsigned int*)&sB[buf][rb_ * 64],      \
          16, 0, 0);                                                                \
    }                                                                               \
  }

  STAGE(0, 0);
  __syncthreads();
  int cur = 0;
#pragma unroll 1
  for (int tk = 0; tk < 12; ++tk) {
    if (tk < 11) STAGE(cur ^ 1, (tk + 1) * 64);
#pragma unroll
    for (int kk = 0; kk < 2; ++kk) {
      bf16x8 af[8], bfv[4];
#pragma unroll
      for (int mi = 0; mi < 8; ++mi) {
        int r = wr * 128 + mi * 16 + (l & 15);
        int ch = (kk << 2) + (l >> 4);
        af[mi] = *(const bf16x8*)(&sA[cur][(r << 6) + ((ch ^ (r & 7)) << 3)]);
      }
#pragma unroll
      for (int ni = 0; ni < 4; ++ni) {
        int r = wc * 64 + ni * 16 + (l & 15);
        int ch = (kk << 2) + (l >> 4);
        bfv[ni] = *(const bf16x8*)(&sB[cur][(r << 6) + ((ch ^ (r & 7)) << 3)]);
      }
#pragma unroll
      for (int mi = 0; mi < 8; ++mi)
#pragma unroll
        for (int ni = 0; ni < 4; ++ni)
          acc[mi][ni] = __builtin_amdgcn_mfma_f32_16x16x32_bf16(af[mi], bfv[ni], acc[mi][ni], 0, 0, 0);
    }
    __syncthreads();
    cur ^= 1;
  }

  // ---- epilogue: row/col max (all slots valid/duplicate), scatter via idx ----
  const float NEG = -__builtin_inff();
  float rmax[8][4], cmax[4];
#pragma unroll
  for (int mi = 0; mi < 8; ++mi)
#pragma unroll
    for (int rg = 0; rg < 4; ++rg) rmax[mi][rg] = NEG;
#pragma unroll
  for (int ni = 0; ni < 4; ++ni) cmax[ni] = NEG;

#pragma unroll
  for (int mi = 0; mi < 8; ++mi)
#pragma unroll
    for (int ni = 0; ni < 4; ++ni)
#pragma unroll
      for (int rg = 0; rg < 4; ++rg) {
        float v = acc[mi][ni][rg];
        rmax[mi][rg] = fmaxf(rmax[mi][rg], v);
        cmax[ni] = fmaxf(cmax[ni], v);
      }
#pragma unroll
  for (int mi = 0; mi < 8; ++mi)
#pragma unroll
    for (int rg = 0; rg < 4; ++rg) {
      float v = rmax[mi][rg];
      v = fmaxf(v, __shfl_xor(v, 1));
      v = fmaxf(v, __shfl_xor(v, 2));
      v = fmaxf(v, __shfl_xor(v, 4));
      v = fmaxf(v, __shfl_xor(v, 8));
      rmax[mi][rg] = v;
    }
#pragma unroll
  for (int ni = 0; ni < 4; ++ni) {
    float v = cmax[ni];
    v = fmaxf(v, __shfl_xor(v, 16));
    v = fmaxf(v, __shfl_xor(v, 32));
    cmax[ni] = v;
  }
  // rows: slots (mi,rg) 0..31; lane (l&15) publishes slots {l&15, 16+(l&15)}
#pragma unroll
  for (int mi = 0; mi < 8; ++mi)
#pragma unroll
    for (int rg = 0; rg < 4; ++rg) {
      if (((mi * 4 + rg) & 15) == (l & 15)) {
        int p = i0 + wr * 128 + mi * 16 + ((l >> 4) << 2) + rg;
        p = p < NV1 - 1 ? p : NV1 - 1;
        int orow = idx1[b * SS + p];
        atomicMax(&rowkey[b * SS + orow], fkey(rmax[mi][rg]));
      }
    }
  // cols: lane-group (l>>4)==ni publishes col wc*64+ni*16+(l&15)
#pragma unroll
  for (int ni = 0; ni < 4; ++ni) {
    if ((l >> 4) == ni) {
      int p = j0 + wc * 64 + ni * 16 + (l & 15);
      p = p < NV2 - 1 ? p : NV2 - 1;
      int ocol = idx2[b * SS + p];
      atomicMax(&colkey[b * SS + ocol], fkey(cmax[ni]));
    }
  }
}

// ---------------- K3: finalize scores ----------------
__global__ __launch_bounds__(256) void finalize_kernel(
    const int* __restrict__ mask1, const int* __restrict__ mask2,
    const unsigned* __restrict__ rowkey, const unsigned* __restrict__ colkey,
    float* __restrict__ out) {
  int b = blockIdx.x, t = threadIdx.x;
  float sum = 0.f;
  int cnt = 0;
  for (int s = t; s < SS; s += 256) {
    if (mask1[b * SS + s]) { sum += fdecode(rowkey[b * SS + s]); cnt++; }
    if (mask2[b * SS + s]) { sum += fdecode(colkey[b * SS + s]); cnt++; }
  }
#pragma unroll
  for (int m = 1; m < 64; m <<= 1) {
    sum += __shfl_xor(sum, m);
    cnt += __shfl_xor(cnt, m);
  }
  __shared__ float sS[4];
  __shared__ int sC[4];
  int w = t >> 6, lane = t & 63;
  if (lane == 0) { sS[w] = sum; sC[w] = cnt; }
  __syncthreads();
  if (t == 0) {
    float T = sS[0] + sS[1] + sS[2] + sS[3];
    int C = sC[0] + sC[1] + sC[2] + sC[3];
    out[b] = T / fmaxf((float)C, 1.0f);
  }
}

extern "C" void kernel_launch(void* const* d_in, const int* in_sizes, int n_in,
                              void* d_out, int out_size, void* d_ws, size_t ws_size,
                              hipStream_t stream) {
  const float* emb1 = (const float*)d_in[0];
  const float* emb2 = (const float*)d_in[1];
  const int* mask1 = (const int*)d_in[2];
  const int* mask2 = (const int*)d_in[3];
  float* out = (float*)d_out;

  unsigned short* wsA = (unsigned short*)d_ws;              // 25.2 MB
  unsigned short* wsB = wsA + (size_t)NROW * DD;            // 25.2 MB
  unsigned* rowkey = (unsigned*)(wsB + (size_t)NROW * DD);  // 64 KB
  unsigned* colkey = rowkey + NROW;                         // 64 KB
  int* idx1 = (int*)(colkey + NROW);                        // 64 KB
  int* idx2 = idx1 + NROW;                                  // 64 KB
  int* nv1 = idx2 + NROW;
  int* nv2 = nv1 + BB;
  int* nt1 = nv2 + BB;
  int* nt2 = nt1 + BB;

  index_kernel<<<64, 64, 0, stream>>>(mask1, mask2, idx1, idx2, nv1, nv2, nt1, nt2, rowkey, colkey);
  norm_cvt_kernel<<<8192, 256, 0, stream>>>(emb1, emb2, idx1, idx2, nv1, nv2, wsA, wsB);
  simmax_kernel<<<128, 512, 0, stream>>>(wsA, wsB, idx1, idx2, nv1, nv2, nt1, nt2, rowkey, colkey);
  finalize_kernel<<<BB, 256, 0, stream>>>(mask1, mask2, rowkey, colkey, out);
}

// Round 8
// 153.084 us; speedup vs baseline: 1.1840x; 1.1840x over previous
//
#include <hip/hip_runtime.h>

#define BB 32
#define SS 512
#define DD 768
#define NROW (BB * SS)  // 16384 rows per input

typedef float f32x4 __attribute__((ext_vector_type(4)));
typedef short bf16x8 __attribute__((ext_vector_type(8)));

// order-preserving float -> uint key (monotone under unsigned compare)
__device__ __forceinline__ unsigned fkey(float f) {
  unsigned u = __float_as_uint(f);
  return (u & 0x80000000u) ? ~u : (u | 0x80000000u);
}
__device__ __forceinline__ float fdecode(unsigned k) {
  return __uint_as_float((k & 0x80000000u) ? (k & 0x7fffffffu) : ~k);
}
// f32 -> bf16 round-to-nearest-even
__device__ __forceinline__ unsigned short cvt_bf16(float f) {
  unsigned u = __float_as_uint(f);
  u += 0x7fffu + ((u >> 16) & 1u);
  return (unsigned short)(u >> 16);
}

// ---------------- K0: valid-index compaction + key init ----------------
// one wave per (batch, side): idx[p] = p-th valid row, nv, nt = ceil(nv/128).
__global__ __launch_bounds__(64) void index_kernel(
    const int* __restrict__ mask1, const int* __restrict__ mask2,
    int* __restrict__ idx1, int* __restrict__ idx2,
    int* __restrict__ nv1, int* __restrict__ nv2,
    int* __restrict__ nt1, int* __restrict__ nt2,
    unsigned* __restrict__ rowkey, unsigned* __restrict__ colkey) {
  int side = blockIdx.x & 1, b = blockIdx.x >> 1;
  const int* m = (side ? mask2 : mask1) + b * SS;
  unsigned* key = (side ? colkey : rowkey) + b * SS;
  int* idx = (side ? idx2 : idx1) + b * SS;
  int l = threadIdx.x;
  int nv = 0;
#pragma unroll
  for (int c = 0; c < 8; ++c) {
    int e = c * 64 + l;
    int v = m[e];
    key[e] = 0x007fffffu;  // fkey(-inf)
    unsigned long long bal = __ballot(v != 0);
    int pos = nv + __popcll(bal & ((1ull << l) - 1ull));
    if (v) idx[pos] = e;
    nv += __popcll(bal);
  }
  if (l == 0) {
    (side ? nv2 : nv1)[b] = nv;
    (side ? nt2 : nt1)[b] = (nv + 127) >> 7;  // 128-row tiles
  }
}

// ---------------- K1: normalize valid rows -> bf16, COMPACTED linear ----------------
__global__ __launch_bounds__(256) void norm_cvt_kernel(
    const float* __restrict__ emb1, const float* __restrict__ emb2,
    const int* __restrict__ idx1, const int* __restrict__ idx2,
    const int* __restrict__ nv1, const int* __restrict__ nv2,
    unsigned short* __restrict__ wsA, unsigned short* __restrict__ wsB) {
  int wave = blockIdx.x * 4 + (threadIdx.x >> 6);  // 32768 waves = slots
  int lane = threadIdx.x & 63;
  int side = wave >> 14;
  int pg = wave & 16383;
  int b = pg >> 9, p = pg & 511;
  int nv = (side ? nv2 : nv1)[b];
  if (p >= nv) return;  // wave-uniform skip
  int orig = (side ? idx2 : idx1)[b * SS + p];
  const float* src = (side ? emb2 : emb1) + ((size_t)b * SS + orig) * DD;
  float4 v[3];
  float s = 0.f;
#pragma unroll
  for (int q = 0; q < 3; ++q) {
    v[q] = ((const float4*)src)[q * 64 + lane];
    s += v[q].x * v[q].x + v[q].y * v[q].y + v[q].z * v[q].z + v[q].w * v[q].w;
  }
#pragma unroll
  for (int m = 1; m < 64; m <<= 1) s += __shfl_xor(s, m);
  float inv = 1.0f / fmaxf(sqrtf(s), 1e-8f);
  unsigned short* dst = (side ? wsB : wsA) + ((size_t)b * SS + p) * DD;
#pragma unroll
  for (int q = 0; q < 3; ++q) {
    ushort4 u;
    u.x = cvt_bf16(v[q].x * inv); u.y = cvt_bf16(v[q].y * inv);
    u.z = cvt_bf16(v[q].z * inv); u.w = cvt_bf16(v[q].w * inv);
    *(ushort4*)(dst + q * 256 + lane * 4) = u;  // coalesced
  }
}

// ---------------- K2: 128x128 bf16 MFMA tile + row/col max ----------------
// 4 waves (2x2 of 64x64), BK=64, dbuf gload_lds from COMPACTED contiguous rows
// (clamped padding), XOR source-swizzle, idx only in epilogue scatter.
__global__ __launch_bounds__(256) void simmax_kernel(
    const unsigned short* __restrict__ wsA, const unsigned short* __restrict__ wsB,
    const int* __restrict__ idx1, const int* __restrict__ idx2,
    const int* __restrict__ nv1, const int* __restrict__ nv2,
    const int* __restrict__ nt1, const int* __restrict__ nt2,
    unsigned* __restrict__ rowkey, unsigned* __restrict__ colkey) {
  int x = blockIdx.x;
  int b = x & 31;          // all 16 tiles of batch b stride-32 => same XCD (b&7)
  int tile = x >> 5;       // 0..15
  int ti = tile >> 2, tj = tile & 3;
  if (ti >= nt1[b] || tj >= nt2[b]) return;
  int NV1 = nv1[b], NV2 = nv2[b];
  int i0 = ti << 7, j0 = tj << 7;
  __shared__ __align__(16) unsigned short sA[2][128 * 64];
  __shared__ __align__(16) unsigned short sB[2][128 * 64];
  int t = threadIdx.x, l = t & 63, wid = t >> 6, wr = wid >> 1, wc = wid & 1;
  int rsub = l >> 3, csub = l & 7;
  int csw = (csub ^ rsub) << 3;  // XOR-swizzled source chunk (elements)
  const unsigned short* gA = wsA + (size_t)b * SS * DD;
  const unsigned short* gB = wsB + (size_t)b * SS * DD;
  size_t offA[4], offB[4];
#pragma unroll
  for (int j = 0; j < 4; ++j) {
    int rowblk = (wid * 4 + j) * 8;   // 4 waves x 4 j x 8 rows = 128
    int pa = i0 + rowblk + rsub, pb = j0 + rowblk + rsub;
    pa = pa < NV1 - 1 ? pa : NV1 - 1;  // clamp padding to last valid slot
    pb = pb < NV2 - 1 ? pb : NV2 - 1;
    offA[j] = (size_t)pa * DD + csw;
    offB[j] = (size_t)pb * DD + csw;
  }

  f32x4 acc[4][4] = {};

#define STAGE(buf, k0)                                                                  \
  {                                                                                     \
    _Pragma("unroll") for (int j = 0; j < 4; ++j) {                                     \
      int rowblk = (wid * 4 + j) * 8;                                                   \
      __builtin_amdgcn_global_load_lds(                                                 \
          (const __attribute__((address_space(1))) unsigned int*)(gA + offA[j] + (k0)), \
          (__attribute__((address_space(3))) unsigned int*)&sA[buf][rowblk * 64],       \
          16, 0, 0);                                                                    \
      __builtin_amdgcn_global_load_lds(                                                 \
          (const __attribute__((address_space(1))) unsigned int*)(gB + offB[j] + (k0)), \
          (__attribute__((address_space(3))) unsigned int*)&sB[buf][rowblk * 64],       \
          16, 0, 0);                                                                    \
    }                                                                                   \
  }

  STAGE(0, 0);
  __syncthreads();
  int cur = 0;
#pragma unroll 1
  for (int tk = 0; tk < 12; ++tk) {
    if (tk < 11) STAGE(cur ^ 1, (tk + 1) * 64);
#pragma unroll
    for (int kk = 0; kk < 2; ++kk) {
      bf16x8 af[4], bfv[4];
#pragma unroll
      for (int mi = 0; mi < 4; ++mi) {
        int r = wr * 64 + mi * 16 + (l & 15);
        int ch = (kk << 2) + (l >> 4);
        af[mi] = *(const bf16x8*)(&sA[cur][(r << 6) + ((ch ^ (r & 7)) << 3)]);
      }
#pragma unroll
      for (int ni = 0; ni < 4; ++ni) {
        int r = wc * 64 + ni * 16 + (l & 15);
        int ch = (kk << 2) + (l >> 4);
        bfv[ni] = *(const bf16x8*)(&sB[cur][(r << 6) + ((ch ^ (r & 7)) << 3)]);
      }
#pragma unroll
      for (int mi = 0; mi < 4; ++mi)
#pragma unroll
        for (int ni = 0; ni < 4; ++ni)
          acc[mi][ni] = __builtin_amdgcn_mfma_f32_16x16x32_bf16(af[mi], bfv[ni], acc[mi][ni], 0, 0, 0);
    }
    __syncthreads();
    cur ^= 1;
  }

  // ---- epilogue: row/col max (all slots valid or duplicates), scatter via idx ----
  const float NEG = -__builtin_inff();
  float rmax[4][4], cmax[4];
#pragma unroll
  for (int mi = 0; mi < 4; ++mi)
#pragma unroll
    for (int rg = 0; rg < 4; ++rg) rmax[mi][rg] = NEG;
#pragma unroll
  for (int ni = 0; ni < 4; ++ni) cmax[ni] = NEG;

#pragma unroll
  for (int mi = 0; mi < 4; ++mi)
#pragma unroll
    for (int ni = 0; ni < 4; ++ni)
#pragma unroll
      for (int rg = 0; rg < 4; ++rg) {
        float v = acc[mi][ni][rg];
        rmax[mi][rg] = fmaxf(rmax[mi][rg], v);
        cmax[ni] = fmaxf(cmax[ni], v);
      }
#pragma unroll
  for (int mi = 0; mi < 4; ++mi)
#pragma unroll
    for (int rg = 0; rg < 4; ++rg) {
      float v = rmax[mi][rg];
      v = fmaxf(v, __shfl_xor(v, 1));
      v = fmaxf(v, __shfl_xor(v, 2));
      v = fmaxf(v, __shfl_xor(v, 4));
      v = fmaxf(v, __shfl_xor(v, 8));
      rmax[mi][rg] = v;
    }
#pragma unroll
  for (int ni = 0; ni < 4; ++ni) {
    float v = cmax[ni];
    v = fmaxf(v, __shfl_xor(v, 16));
    v = fmaxf(v, __shfl_xor(v, 32));
    cmax[ni] = v;
  }
  int selm = (l >> 2) & 3, selr = l & 3, seln = (l >> 4) & 3;
  float rv = rmax[0][0], cv = cmax[0];
#pragma unroll
  for (int mi = 0; mi < 4; ++mi)
#pragma unroll
    for (int rg = 0; rg < 4; ++rg)
      if (selm == mi && selr == rg) rv = rmax[mi][rg];
#pragma unroll
  for (int ni = 0; ni < 4; ++ni)
    if (seln == ni) cv = cmax[ni];
  int rl = selm * 16 + ((l >> 4) & 3) * 4 + selr;  // bijection over 64 rows
  int cl = seln * 16 + (l & 15);                   // bijection over 64 cols
  int pr = i0 + wr * 64 + rl;
  pr = pr < NV1 - 1 ? pr : NV1 - 1;
  int pc = j0 + wc * 64 + cl;
  pc = pc < NV2 - 1 ? pc : NV2 - 1;
  int orow = idx1[b * SS + pr];
  int ocol = idx2[b * SS + pc];
  atomicMax(&rowkey[b * SS + orow], fkey(rv));
  atomicMax(&colkey[b * SS + ocol], fkey(cv));
}

// ---------------- K3: finalize scores ----------------
__global__ __launch_bounds__(256) void finalize_kernel(
    const int* __restrict__ mask1, const int* __restrict__ mask2,
    const unsigned* __restrict__ rowkey, const unsigned* __restrict__ colkey,
    float* __restrict__ out) {
  int b = blockIdx.x, t = threadIdx.x;
  float sum = 0.f;
  int cnt = 0;
  for (int s = t; s < SS; s += 256) {
    if (mask1[b * SS + s]) { sum += fdecode(rowkey[b * SS + s]); cnt++; }
    if (mask2[b * SS + s]) { sum += fdecode(colkey[b * SS + s]); cnt++; }
  }
#pragma unroll
  for (int m = 1; m < 64; m <<= 1) {
    sum += __shfl_xor(sum, m);
    cnt += __shfl_xor(cnt, m);
  }
  __shared__ float sS[4];
  __shared__ int sC[4];
  int w = t >> 6, lane = t & 63;
  if (lane == 0) { sS[w] = sum; sC[w] = cnt; }
  __syncthreads();
  if (t == 0) {
    float T = sS[0] + sS[1] + sS[2] + sS[3];
    int C = sC[0] + sC[1] + sC[2] + sC[3];
    out[b] = T / fmaxf((float)C, 1.0f);
  }
}

extern "C" void kernel_launch(void* const* d_in, const int* in_sizes, int n_in,
                              void* d_out, int out_size, void* d_ws, size_t ws_size,
                              hipStream_t stream) {
  const float* emb1 = (const float*)d_in[0];
  const float* emb2 = (const float*)d_in[1];
  const int* mask1 = (const int*)d_in[2];
  const int* mask2 = (const int*)d_in[3];
  float* out = (float*)d_out;

  unsigned short* wsA = (unsigned short*)d_ws;              // 25.2 MB
  unsigned short* wsB = wsA + (size_t)NROW * DD;            // 25.2 MB
  unsigned* rowkey = (unsigned*)(wsB + (size_t)NROW * DD);  // 64 KB
  unsigned* colkey = rowkey + NROW;                         // 64 KB
  int* idx1 = (int*)(colkey + NROW);                        // 64 KB
  int* idx2 = idx1 + NROW;                                  // 64 KB
  int* nv1 = idx2 + NROW;
  int* nv2 = nv1 + BB;
  int* nt1 = nv2 + BB;
  int* nt2 = nt1 + BB;

  index_kernel<<<64, 64, 0, stream>>>(mask1, mask2, idx1, idx2, nv1, nv2, nt1, nt2, rowkey, colkey);
  norm_cvt_kernel<<<8192, 256, 0, stream>>>(emb1, emb2, idx1, idx2, nv1, nv2, wsA, wsB);
  simmax_kernel<<<512, 256, 0, stream>>>(wsA, wsB, idx1, idx2, nv1, nv2, nt1, nt2, rowkey, colkey);
  finalize_kernel<<<BB, 256, 0, stream>>>(mask1, mask2, rowkey, colkey, out);
}